// Round 1
// baseline (63.551 us; speedup 1.0000x reference)
//
#include <hip/hip_runtime.h>
#include <math.h>

#define RED_BLOCKS 1024
#define BLK 256
#define HDIM 64

// ---------------- Stage 1: per-block partial sum / sumsq (f64, deterministic) ----------------
__global__ void k_reduce_partial(const float* __restrict__ hu, int n,
                                 double* __restrict__ part) {
  __shared__ double ls[BLK];
  __shared__ double lq[BLK];
  double s = 0.0, q = 0.0;
  for (int i = blockIdx.x * BLK + threadIdx.x; i < n; i += gridDim.x * BLK) {
    double v = (double)hu[i];
    s += v;
    q += v * v;
  }
  ls[threadIdx.x] = s;
  lq[threadIdx.x] = q;
  __syncthreads();
  for (int off = BLK / 2; off > 0; off >>= 1) {
    if (threadIdx.x < off) {
      ls[threadIdx.x] += ls[threadIdx.x + off];
      lq[threadIdx.x] += lq[threadIdx.x + off];
    }
    __syncthreads();
  }
  if (threadIdx.x == 0) {
    part[blockIdx.x] = ls[0];
    part[RED_BLOCKS + blockIdx.x] = lq[0];
  }
}

// ---------------- Stage 2: final reduce -> mu, 1/(std+eps) ----------------
__global__ void k_reduce_final(const double* __restrict__ part, int n,
                               float* __restrict__ stats) {
  __shared__ double ls[BLK];
  __shared__ double lq[BLK];
  double s = 0.0, q = 0.0;
  for (int i = threadIdx.x; i < RED_BLOCKS; i += BLK) {
    s += part[i];
    q += part[RED_BLOCKS + i];
  }
  ls[threadIdx.x] = s;
  lq[threadIdx.x] = q;
  __syncthreads();
  for (int off = BLK / 2; off > 0; off >>= 1) {
    if (threadIdx.x < off) {
      ls[threadIdx.x] += ls[threadIdx.x + off];
      lq[threadIdx.x] += lq[threadIdx.x + off];
    }
    __syncthreads();
  }
  if (threadIdx.x == 0) {
    double sum = ls[0], sumsq = lq[0];
    double mu = sum / (double)n;
    double var = (sumsq - sum * sum / (double)n) / (double)(n - 1);
    if (var < 0.0) var = 0.0;
    double sigma = sqrt(var) + 1e-8;  // torch-style unbiased std + EPS
    stats[0] = (float)mu;
    stats[1] = (float)(1.0 / sigma);
  }
}

// ---------------- Stage 3: per-node s_nei / s_self ----------------
// a[u] = sum_{v in nbr(u)} h0[v] = (sum hu[v] - 4*mu) * inv_sigma
// c[u] = (hu[u]-mu)*inv_sigma
// s_nei[u]  = sum_j relu(b1_j + a*Wn1_j + c*Ws1_j) * Wnei2_j
// s_self[u] = same with Wself2_j
__global__ void k_layer1(const float* __restrict__ hu,
                         const int* __restrict__ nbr,
                         const float* __restrict__ Wn1,
                         const float* __restrict__ Ws1,
                         const float* __restrict__ B1,
                         const float* __restrict__ Wn2,
                         const float* __restrict__ Ws2,
                         const float* __restrict__ stats,
                         float* __restrict__ snei,
                         float* __restrict__ sself,  // may be null
                         int n) {
  __shared__ float wn1[HDIM], ws1[HDIM], bb1[HDIM], wn2[HDIM], ws2[HDIM];
  int t = threadIdx.x;
  if (t < HDIM) {
    wn1[t] = Wn1[t];
    ws1[t] = Ws1[t];
    bb1[t] = B1[t];
    wn2[t] = Wn2[t];
    ws2[t] = Ws2[t];
  }
  __syncthreads();
  int u = blockIdx.x * BLK + threadIdx.x;
  if (u >= n) return;
  float mu = stats[0];
  float inv = stats[1];
  int4 nb = ((const int4*)nbr)[u];  // fixed degree 4, contiguous
  float hsum = hu[nb.x] + hu[nb.y] + hu[nb.z] + hu[nb.w];
  float a = (hsum - 4.0f * mu) * inv;
  float c = (hu[u] - mu) * inv;
  float sn = 0.0f, ss = 0.0f;
#pragma unroll
  for (int j = 0; j < HDIM; ++j) {
    float tt = fmaf(a, wn1[j], fmaf(c, ws1[j], bb1[j]));
    float r = fmaxf(tt, 0.0f);
    sn = fmaf(r, wn2[j], sn);
    ss = fmaf(r, ws2[j], ss);
  }
  snei[u] = sn;
  if (sself != nullptr) sself[u] = ss;
}

// ---------------- Stage 4: gather s_nei + tanh ----------------
__global__ void k_layer2(const int* __restrict__ nbr,
                         const float* __restrict__ snei,
                         const float* __restrict__ sself,
                         const float* __restrict__ B2,
                         float* __restrict__ out,
                         int n) {
  int u = blockIdx.x * BLK + threadIdx.x;
  if (u >= n) return;
  int4 nb = ((const int4*)nbr)[u];
  float s = snei[nb.x] + snei[nb.y] + snei[nb.z] + snei[nb.w];
  float d = B2[0] + s + sself[u];
  out[u] = 0.3f * tanhf(d);
}

// Fallback (small ws): recompute s_self inline instead of reading it.
__global__ void k_layer2_rc(const float* __restrict__ hu,
                            const int* __restrict__ nbr,
                            const float* __restrict__ Wn1,
                            const float* __restrict__ Ws1,
                            const float* __restrict__ B1,
                            const float* __restrict__ Ws2,
                            const float* __restrict__ stats,
                            const float* __restrict__ snei,
                            const float* __restrict__ B2,
                            float* __restrict__ out,
                            int n) {
  __shared__ float wn1[HDIM], ws1[HDIM], bb1[HDIM], ws2[HDIM];
  int t = threadIdx.x;
  if (t < HDIM) {
    wn1[t] = Wn1[t];
    ws1[t] = Ws1[t];
    bb1[t] = B1[t];
    ws2[t] = Ws2[t];
  }
  __syncthreads();
  int u = blockIdx.x * BLK + threadIdx.x;
  if (u >= n) return;
  float mu = stats[0];
  float inv = stats[1];
  int4 nb = ((const int4*)nbr)[u];
  float hsum = hu[nb.x] + hu[nb.y] + hu[nb.z] + hu[nb.w];
  float a = (hsum - 4.0f * mu) * inv;
  float c = (hu[u] - mu) * inv;
  float ss = 0.0f;
#pragma unroll
  for (int j = 0; j < HDIM; ++j) {
    float tt = fmaf(a, wn1[j], fmaf(c, ws1[j], bb1[j]));
    float r = fmaxf(tt, 0.0f);
    ss = fmaf(r, ws2[j], ss);
  }
  float s = snei[nb.x] + snei[nb.y] + snei[nb.z] + snei[nb.w];
  float d = B2[0] + s + ss;
  out[u] = 0.3f * tanhf(d);
}

extern "C" void kernel_launch(void* const* d_in, const int* in_sizes, int n_in,
                              void* d_out, int out_size, void* d_ws, size_t ws_size,
                              hipStream_t stream) {
  const float* hu  = (const float*)d_in[0];
  const int*   nbr = (const int*)d_in[1];
  // d_in[2] = neighbor_offsets: fixed-degree-4 CSR (arange*4), not needed.
  const float* Wn1 = (const float*)d_in[3];
  const float* Ws1 = (const float*)d_in[4];
  const float* B1  = (const float*)d_in[5];
  const float* Wn2 = (const float*)d_in[6];
  const float* Ws2 = (const float*)d_in[7];
  const float* B2  = (const float*)d_in[8];
  float* out = (float*)d_out;
  const int n = in_sizes[0];

  char* ws = (char*)d_ws;
  double* part = (double*)ws;                              // 2*RED_BLOCKS*8 = 16 KiB
  float* stats = (float*)(ws + 2 * RED_BLOCKS * 8);        // 8 B
  float* snei  = (float*)(ws + 32768);
  size_t need_full = 32768 + 2 * (size_t)n * sizeof(float);
  size_t need_half = 32768 + (size_t)n * sizeof(float);

  k_reduce_partial<<<RED_BLOCKS, BLK, 0, stream>>>(hu, n, part);
  k_reduce_final<<<1, BLK, 0, stream>>>(part, n, stats);

  int blocks = (n + BLK - 1) / BLK;
  if (ws_size >= need_full) {
    float* sself = snei + n;
    k_layer1<<<blocks, BLK, 0, stream>>>(hu, nbr, Wn1, Ws1, B1, Wn2, Ws2, stats,
                                         snei, sself, n);
    k_layer2<<<blocks, BLK, 0, stream>>>(nbr, snei, sself, B2, out, n);
  } else if (ws_size >= need_half) {
    k_layer1<<<blocks, BLK, 0, stream>>>(hu, nbr, Wn1, Ws1, B1, Wn2, Ws2, stats,
                                         snei, nullptr, n);
    k_layer2_rc<<<blocks, BLK, 0, stream>>>(hu, nbr, Wn1, Ws1, B1, Ws2, stats,
                                            snei, B2, out, n);
  }
}